// Round 5
// baseline (358.777 us; speedup 1.0000x reference)
//
#include <hip/hip_runtime.h>
#include <hip/hip_bf16.h>

// GraphSAGE 2-layer. Project-then-aggregate (aggregation is linear):
//   ycomb = x @ [W1l|W1r]^T   (bf16 MFMA, LDS-staged A with XOR swizzle)
//   CSR build (once): counting-sort edges by tgt
//   h     = csr_mean(ycomb[:, :32]) + b1l + ycomb[:,32:]
//   ycomb = h @ [W2l|W2r]^T
//   out   = log_softmax(relu(csr_mean(ycomb[:, :32]) + b2l + ycomb[:,32:]))

typedef __attribute__((ext_vector_type(8))) __bf16 bf16x8;
typedef __attribute__((ext_vector_type(4))) float f32x4;

constexpr int K1 = 1433;
constexpr int KP1 = 1536;  // B pad: multiple of 128 -> no B guards anywhere
constexpr int BK = 128;    // fp32 cols per LDS step (512 B per row)
constexpr int NSTEP = 12;  // ceil(1433/128)

__device__ __forceinline__ bf16x8 cvt8(const float4 lo, const float4 hi) {
  bf16x8 r;
  r[0] = (__bf16)lo.x; r[1] = (__bf16)lo.y;
  r[2] = (__bf16)lo.z; r[3] = (__bf16)lo.w;
  r[4] = (__bf16)hi.x; r[5] = (__bf16)hi.y;
  r[6] = (__bf16)hi.z; r[7] = (__bf16)hi.w;
  return r;
}

// Convert [W_l; W_r] (each 32 x K fp32) into WB[64][KP] bf16, zero-padded.
__global__ __launch_bounds__(256) void conv_w(const float* __restrict__ Wl,
                                              const float* __restrict__ Wr,
                                              __bf16* __restrict__ out, int K,
                                              int KP) {
  const int t = blockIdx.x * 256 + threadIdx.x;
  if (t >= 64 * KP) return;
  const int c = t / KP, k = t - c * KP;
  float v = 0.0f;
  if (k < K) v = (c < 32) ? Wl[(long)c * K + k] : Wr[(long)(c - 32) * K + k];
  out[t] = (__bf16)v;
}

// Y[N][64] = X[N][1433] @ WB[64][1536]^T.
// 256 thr / 4 waves; block tile 64 rows. A staged fp32->LDS (double-buffered,
// XOR-swizzled 16B units), fragments cvt'd to bf16 at read. B from L2.
// Staging: round j, thread t -> row j*8+(t>>5), 16B at col (t&31)*16: each
// wave-instruction reads 2 rows x 512 B CONTIGUOUS (vs 16-row scatter before).
__global__ __launch_bounds__(256) void gemm_big(const float* __restrict__ X,
                                                const __bf16* __restrict__ WB,
                                                float* __restrict__ Y,
                                                int Nrows) {
  __shared__ float lds[2 * 64 * BK];  // 64 KB
  const int tid = threadIdx.x;
  const int w = tid >> 6, l = tid & 63;
  const int lr = l & 15, lg = l >> 4;
  const int row0 = blockIdx.x * 64;

  // staging coords (thread-invariant across rounds)
  const int scol = (tid & 31) * 4;  // float col within BK window
  const int srow = tid >> 5;        // 0..7 ; round j -> row j*8+srow
  // fragment coords
  const int frow = w * 16 + lr;     // LDS row this lane reads
  const int swz = (lr & 7) << 4;    // byte XOR (row&7 == lr&7 since w*16%8==0)

  f32x4 acc[4];
#pragma unroll
  for (int j = 0; j < 4; ++j) acc[j] = (f32x4){0.f, 0.f, 0.f, 0.f};

  float4 sreg[8];

  auto stage = [&](int s) {
    const int kg = s * BK + scol;
    const bool full = (kg + 3 < K1);
#pragma unroll
    for (int j = 0; j < 8; ++j) {
      int r = row0 + j * 8 + srow;
      if (r >= Nrows) r = Nrows - 1;
      const float* p = X + (long)r * K1 + kg;
      float4 v;
      if (full) {
        v = *reinterpret_cast<const float4*>(p);
      } else {
        v.x = (kg + 0 < K1) ? p[0] : 0.f;
        v.y = (kg + 1 < K1) ? p[1] : 0.f;
        v.z = (kg + 2 < K1) ? p[2] : 0.f;
        v.w = (kg + 3 < K1) ? p[3] : 0.f;
      }
      sreg[j] = v;
    }
  };

  auto commit = [&](int buf) {
    char* base = (char*)(lds + buf * (64 * BK));
#pragma unroll
    for (int j = 0; j < 8; ++j) {
      const int row = j * 8 + srow;
      const int boff = row * 512 + ((scol * 4) ^ ((row & 7) << 4));
      *reinterpret_cast<float4*>(base + boff) = sreg[j];
    }
  };

  auto compute = [&](int buf, int s) {
    const char* base = (const char*)(lds + buf * (64 * BK));
#pragma unroll
    for (int kf = 0; kf < 4; ++kf) {
      const int cb0 = kf * 128 + lg * 32;
      const float4 u = *reinterpret_cast<const float4*>(
          base + frow * 512 + (cb0 ^ swz));
      const float4 v = *reinterpret_cast<const float4*>(
          base + frow * 512 + ((cb0 + 16) ^ swz));
      const bf16x8 af = cvt8(u, v);
#pragma unroll
      for (int ct = 0; ct < 4; ++ct) {
        const bf16x8 bf = *reinterpret_cast<const bf16x8*>(
            WB + (long)(ct * 16 + lr) * KP1 + s * BK + kf * 32 + lg * 8);
        acc[ct] = __builtin_amdgcn_mfma_f32_16x16x32_bf16(af, bf, acc[ct], 0, 0, 0);
      }
    }
  };

  stage(0);
  commit(0);
  __syncthreads();
#pragma unroll 1
  for (int s = 0; s < NSTEP; ++s) {
    if (s + 1 < NSTEP) stage(s + 1);  // loads in flight during compute
    compute(s & 1, s);
    __syncthreads();                   // all reads of buf[s&1] done
    if (s + 1 < NSTEP) commit((s + 1) & 1);
    __syncthreads();                   // writes visible
  }

  // D layout: col = lane&15 (lr), row = lg*4 + reg j
#pragma unroll
  for (int j = 0; j < 4; ++j) {
    const long R = (long)row0 + w * 16 + lg * 4 + j;
    if (R < Nrows) {
#pragma unroll
      for (int ct = 0; ct < 4; ++ct) Y[R * 64 + ct * 16 + lr] = acc[ct][j];
    }
  }
}

// Y[N][64] = X[N][32] @ WB[64][32]^T, single k-step.
__global__ __launch_bounds__(256) void gemm_small(const float* __restrict__ X,
                                                  const __bf16* __restrict__ WB,
                                                  float* __restrict__ Y,
                                                  int Nrows) {
  const int tid = threadIdx.x;
  const int w = tid >> 6, l = tid & 63;
  const int lr = l & 15, lg = l >> 4;
  const long rowbase = (long)blockIdx.x * 64 + (long)w * 16;
  long r0 = rowbase + lr;
  if (r0 >= Nrows) r0 = Nrows - 1;
  const float* px = X + r0 * 32 + lg * 8;
  const __bf16* pw = WB + lr * 32 + lg * 8;

  const float4 lo = *reinterpret_cast<const float4*>(px);
  const float4 hi = *reinterpret_cast<const float4*>(px + 4);
  const bf16x8 af = cvt8(lo, hi);
  f32x4 acc[4];
#pragma unroll
  for (int j = 0; j < 4; ++j) acc[j] = (f32x4){0.f, 0.f, 0.f, 0.f};
#pragma unroll
  for (int t = 0; t < 4; ++t) {
    const bf16x8 bf = *reinterpret_cast<const bf16x8*>(pw + t * 16 * 32);
    acc[t] = __builtin_amdgcn_mfma_f32_16x16x32_bf16(af, bf, acc[t], 0, 0, 0);
  }
#pragma unroll
  for (int j = 0; j < 4; ++j) {
    const long R = rowbase + lg * 4 + j;
    if (R < Nrows) {
#pragma unroll
      for (int ct = 0; ct < 4; ++ct) Y[R * 64 + ct * 16 + lr] = acc[ct][j];
    }
  }
}

// ---------------- CSR build: counting sort edges by tgt ----------------

__global__ __launch_bounds__(256) void hist_deg(const int* __restrict__ ei,
                                                int* __restrict__ deg, int E) {
  const int e = blockIdx.x * 256 + threadIdx.x;
  if (e < E) atomicAdd(&deg[ei[E + e]], 1);
}

__global__ __launch_bounds__(256) void scan_tilesum(const int* __restrict__ deg,
                                                    int* __restrict__ tileSum,
                                                    int n) {
  __shared__ int s[256];
  const int b = blockIdx.x, t = threadIdx.x;
  const int base = b * 2048 + t * 8;
  int v = 0;
#pragma unroll
  for (int j = 0; j < 8; ++j) {
    const int i = base + j;
    if (i < n) v += deg[i];
  }
  s[t] = v;
  __syncthreads();
  for (int d = 128; d > 0; d >>= 1) {
    if (t < d) s[t] += s[t + d];
    __syncthreads();
  }
  if (t == 0) tileSum[b] = s[0];
}

__global__ __launch_bounds__(64) void scan_tileoff(const int* __restrict__ tileSum,
                                                   int* __restrict__ tileOff,
                                                   int nT) {
  const int l = threadIdx.x;
  const int v = (l < nT) ? tileSum[l] : 0;
  int inc = v;
#pragma unroll
  for (int d = 1; d < 64; d <<= 1) {
    const int o = __shfl_up(inc, d);
    if (l >= d) inc += o;
  }
  if (l < nT) tileOff[l] = inc - v;
}

__global__ __launch_bounds__(256) void scan_offsets(const int* __restrict__ deg,
                                                    const int* __restrict__ tileOff,
                                                    int* __restrict__ off, int n) {
  __shared__ int warpTot[4];
  const int b = blockIdx.x, t = threadIdx.x;
  const int base = b * 2048 + t * 8;
  int v[8];
  int s = 0;
#pragma unroll
  for (int j = 0; j < 8; ++j) {
    const int i = base + j;
    v[j] = (i < n) ? deg[i] : 0;
    s += v[j];
  }
  const int l = t & 63, w = t >> 6;
  int inc = s;
#pragma unroll
  for (int d = 1; d < 64; d <<= 1) {
    const int o = __shfl_up(inc, d);
    if (l >= d) inc += o;
  }
  if (l == 63) warpTot[w] = inc;
  __syncthreads();
  int wo = 0;
  for (int k = 0; k < w; ++k) wo += warpTot[k];
  int ex = wo + (inc - s) + tileOff[b];
#pragma unroll
  for (int j = 0; j < 8; ++j) {
    const int i = base + j;
    if (i < n) {
      off[i] = ex;
      ex += v[j];
    }
  }
}

__global__ __launch_bounds__(256) void scatter_src(const int* __restrict__ ei,
                                                   const int* __restrict__ off,
                                                   int* __restrict__ fill,
                                                   int* __restrict__ ssrc,
                                                   int E) {
  const int e = blockIdx.x * 256 + threadIdx.x;
  if (e < E) {
    const int t = ei[E + e];
    const int p = off[t] + atomicAdd(&fill[t], 1);
    ssrc[p] = ei[e];
  }
}

// ---------------- fused aggregation ----------------
template <int FINAL>
__global__ __launch_bounds__(256) void agg_fused(
    const int* __restrict__ off, const int* __restrict__ deg,
    const int* __restrict__ ssrc, const float* __restrict__ Y,
    const float* __restrict__ bias, float* __restrict__ out, int N) {
  const int t = blockIdx.x * 256 + threadIdx.x;
  const int i = t >> 5, c = t & 31;
  if (i >= N) return;
  const int st = off[i], d = deg[i];
  float acc = 0.0f;
  int e = 0;
  for (; e + 4 <= d; e += 4) {
    const int s0 = ssrc[st + e + 0];
    const int s1 = ssrc[st + e + 1];
    const int s2 = ssrc[st + e + 2];
    const int s3 = ssrc[st + e + 3];
    acc += Y[(long)s0 * 64 + c] + Y[(long)s1 * 64 + c] +
           Y[(long)s2 * 64 + c] + Y[(long)s3 * 64 + c];
  }
  for (; e < d; ++e) acc += Y[(long)ssrc[st + e] * 64 + c];
  const float mean = acc / fmaxf((float)d, 1.0f);
  float v = mean + bias[c] + Y[(long)i * 64 + 32 + c];
  if (FINAL) {
    v = fmaxf(v, 0.0f);
    float m = v;
#pragma unroll
    for (int dd = 16; dd >= 1; dd >>= 1) m = fmaxf(m, __shfl_xor(m, dd));
    const float ex = __expf(v - m);
    float s = ex;
#pragma unroll
    for (int dd = 16; dd >= 1; dd >>= 1) s += __shfl_xor(s, dd);
    out[(long)i * 32 + c] = (v - m) - __logf(s);
  } else {
    out[(long)i * 32 + c] = v;
  }
}

extern "C" void kernel_launch(void* const* d_in, const int* in_sizes, int n_in,
                              void* d_out, int out_size, void* d_ws,
                              size_t ws_size, hipStream_t stream) {
  const float* x = (const float*)d_in[0];
  const int* ei = (const int*)d_in[1];
  const float* W1l = (const float*)d_in[2];
  const float* b1l = (const float*)d_in[3];
  const float* W1r = (const float*)d_in[4];
  const float* W2l = (const float*)d_in[5];
  const float* b2l = (const float*)d_in[6];
  const float* W2r = (const float*)d_in[7];
  float* out = (float*)d_out;

  const int N = in_sizes[0] / K1;
  const int E = in_sizes[1] / 2;
  const int nTiles = (N + 2047) / 2048;

  char* ws = (char*)d_ws;
  size_t o = 0;
  auto alloc = [&](size_t bytes) {
    void* p = ws + o;
    o += (bytes + 255) & ~(size_t)255;
    return p;
  };
  float* ycomb = (float*)alloc((size_t)N * 64 * 4);
  float* h = (float*)alloc((size_t)N * 32 * 4);
  __bf16* wb1 = (__bf16*)alloc((size_t)64 * KP1 * 2);
  __bf16* wb2 = (__bf16*)alloc((size_t)64 * 32 * 2);
  int* deg = (int*)alloc((size_t)N * 4);
  int* off = (int*)alloc((size_t)N * 4);
  int* fill = (int*)alloc((size_t)N * 4);
  int* ssrc = (int*)alloc((size_t)E * 4);
  int* tileSum = (int*)alloc(64 * 4);
  int* tileOff = (int*)alloc(64 * 4);

  conv_w<<<(64 * KP1 + 255) / 256, 256, 0, stream>>>(W1l, W1r, wb1, K1, KP1);
  conv_w<<<(64 * 32 + 255) / 256, 256, 0, stream>>>(W2l, W2r, wb2, 32, 32);
  hipMemsetAsync(deg, 0, (size_t)N * 4, stream);
  hipMemsetAsync(fill, 0, (size_t)N * 4, stream);
  hist_deg<<<(E + 255) / 256, 256, 0, stream>>>(ei, deg, E);
  scan_tilesum<<<nTiles, 256, 0, stream>>>(deg, tileSum, N);
  scan_tileoff<<<1, 64, 0, stream>>>(tileSum, tileOff, nTiles);
  scan_offsets<<<nTiles, 256, 0, stream>>>(deg, tileOff, off, N);
  scatter_src<<<(E + 255) / 256, 256, 0, stream>>>(ei, off, fill, ssrc, E);

  // Layer 1
  gemm_big<<<(N + 63) / 64, 256, 0, stream>>>(x, wb1, ycomb, N);
  agg_fused<0><<<(N * 32 + 255) / 256, 256, 0, stream>>>(off, deg, ssrc, ycomb,
                                                         b1l, h, N);
  // Layer 2
  gemm_small<<<(N + 63) / 64, 256, 0, stream>>>(h, wb2, ycomb, N);
  agg_fused<1><<<(N * 32 + 255) / 256, 256, 0, stream>>>(off, deg, ssrc, ycomb,
                                                         b2l, out, N);
}

// Round 7
// 301.379 us; speedup vs baseline: 1.1905x; 1.1905x over previous
//
#include <hip/hip_runtime.h>
#include <hip/hip_bf16.h>

// GraphSAGE 2-layer. Project-then-aggregate (aggregation is linear):
//   ycomb = x @ [W1l|W1r]^T   (bf16 MFMA; A AND B staged via global_load_lds,
//                              pre-swizzled sources, LDS-only inner loop)
//   CSR build (once): counting-sort edges by tgt
//   h     = csr_mean(ycomb[:, :32]) + b1l + ycomb[:,32:]
//   ycomb = h @ [W2l|W2r]^T
//   out   = log_softmax(relu(csr_mean(ycomb[:, :32]) + b2l + ycomb[:,32:]))

typedef __attribute__((ext_vector_type(8))) __bf16 bf16x8;
typedef __attribute__((ext_vector_type(4))) float f32x4;

constexpr int K1 = 1433;
constexpr int KP1 = 1536;  // B pad (bf16): no B guards anywhere
constexpr int BK = 32;     // k per step
constexpr int NS = 45;     // ceil(1433/32); k>=1433 contributes A*0 via B pad
constexpr int BM = 128;    // rows per block

__device__ __forceinline__ void gload_lds16(const void* g, void* l) {
  // Address-space casts must route through uintptr_t (pointer->pointer
  // addrspace reinterpret_cast is rejected; integer->AS-pointer is accepted).
  __builtin_amdgcn_global_load_lds(
      reinterpret_cast<const __attribute__((address_space(1))) void*>(
          reinterpret_cast<uintptr_t>(g)),
      reinterpret_cast<__attribute__((address_space(3))) void*>(
          reinterpret_cast<uintptr_t>(l)),
      16, 0, 0);
}

__device__ __forceinline__ bf16x8 cvt8(const float4 lo, const float4 hi) {
  bf16x8 r;
  r[0] = (__bf16)lo.x; r[1] = (__bf16)lo.y;
  r[2] = (__bf16)lo.z; r[3] = (__bf16)lo.w;
  r[4] = (__bf16)hi.x; r[5] = (__bf16)hi.y;
  r[6] = (__bf16)hi.z; r[7] = (__bf16)hi.w;
  return r;
}

// Convert [W_l; W_r] (each 32 x K fp32) into WB[64][KP] bf16, zero-padded.
__global__ __launch_bounds__(256) void conv_w(const float* __restrict__ Wl,
                                              const float* __restrict__ Wr,
                                              __bf16* __restrict__ out, int K,
                                              int KP) {
  const int t = blockIdx.x * 256 + threadIdx.x;
  if (t >= 64 * KP) return;
  const int c = t / KP, k = t - c * KP;
  float v = 0.0f;
  if (k < K) v = (c < 32) ? Wl[(long)c * K + k] : Wr[(long)(c - 32) * K + k];
  out[t] = (__bf16)v;
}

// Y[N][64] = X[N][1433] @ WB[64][1536]^T.
// m97 structure: the k-loop's ONLY global accesses are global_load_lds (A and
// B) -> no register global loads -> no in-order-vmcnt drain inside compute.
// LDS layouts (linear, written by the DMA engine):
//   A[128][32] f32 : LDS[r][chunk p] = X[r][p ^ (r&7)]     (16B chunks, 8/row)
//   B[64][32] bf16 : LDS[r][chunk p] = WB[r][p ^ ((r>>1)&3)] (16B chunks, 4/row)
// achieved by pre-swizzling the per-lane GLOBAL source address; uniform
// 8-lanes-per-bank-quad on all ds_read patterns (= full LDS bandwidth).
__global__ __launch_bounds__(256) void gemm_big(const float* __restrict__ X,
                                                const __bf16* __restrict__ WB,
                                                float* __restrict__ Y,
                                                int Nrows) {
  __shared__ float ldsA[2][BM][BK];      // 2 x 16 KB
  __shared__ __bf16 ldsB[2][64][BK];     // 2 x 4 KB
  const int tid = threadIdx.x;
  const int w = tid >> 6, l = tid & 63;
  const int lr = l & 15, lg = l >> 4;
  const int row0 = blockIdx.x * BM;

  // ---- staging source addresses (swizzled) ----
  // A instr i (i=0..3): lane l -> global row row0+w*32+i*8+(l>>3),
  //                     chunk (l&7)^(l>>3); LDS dest base (w*32+i*8) row.
  const int aRowIn = (l >> 3);            // 0..7
  const int aChunk = (l & 7) ^ aRowIn;    // swizzled 16B chunk
  long aRow[4];
#pragma unroll
  for (int i = 0; i < 4; ++i) {
    long r = (long)row0 + w * 32 + i * 8 + aRowIn;
    if (r >= Nrows) r = Nrows - 1;
    aRow[i] = r;
  }
  const float* const pAmax = X + (size_t)Nrows * K1 - 4;  // clamp: stay in buf
  // B: lane l -> row w*16+(l>>2), chunk (l&3)^((l>>3)&3)
  const int bRow = w * 16 + (l >> 2);
  const int bChunk = (l & 3) ^ ((l >> 3) & 3);
  const __bf16* const pB0 = WB + (long)bRow * KP1 + bChunk * 8;

  auto stage = [&](int s, int buf) {
    const int k0 = s * BK;
#pragma unroll
    for (int i = 0; i < 4; ++i) {
      const float* g = X + aRow[i] * K1 + k0 + aChunk * 4;
      if (g > pAmax) g = pAmax;  // finite garbage * B-zero-pad = 0
      gload_lds16(g, &ldsA[buf][w * 32 + i * 8][0]);
    }
    gload_lds16(pB0 + k0, &ldsB[buf][w * 16][0]);
  };

  f32x4 acc[2][4];
#pragma unroll
  for (int t = 0; t < 2; ++t)
#pragma unroll
    for (int j = 0; j < 4; ++j) acc[t][j] = (f32x4){0.f, 0.f, 0.f, 0.f};

  const int swzA = lr & 7;          // row&7 for this lane's A-frag rows
  const int swzB = (lr >> 1) & 3;   // (row>>1)&3 for this lane's B-frag rows

  stage(0, 0);
#pragma unroll 1
  for (int s = 0; s < NS; ++s) {
    const int buf = s & 1;
    if (s + 1 < NS) stage(s + 1, buf ^ 1);
    __syncthreads();  // stage(s) complete & visible (vmcnt drain accepted:
                      // 4 blocks/CU provide the BW overlap)
    // ---- compute from LDS only ----
    bf16x8 bfrag[4];
#pragma unroll
    for (int ct = 0; ct < 4; ++ct) {
      const int br = ct * 16 + lr;
      bfrag[ct] = *reinterpret_cast<const bf16x8*>(
          &ldsB[buf][br][(lg ^ swzB) * 8]);
    }
#pragma unroll
    for (int t = 0; t < 2; ++t) {
      const int fr = w * 32 + t * 16 + lr;
      const float4 u = *reinterpret_cast<const float4*>(
          &ldsA[buf][fr][((lg * 2 + 0) ^ swzA) * 4]);
      const float4 v = *reinterpret_cast<const float4*>(
          &ldsA[buf][fr][((lg * 2 + 1) ^ swzA) * 4]);
      const bf16x8 af = cvt8(u, v);
#pragma unroll
      for (int ct = 0; ct < 4; ++ct)
        acc[t][ct] =
            __builtin_amdgcn_mfma_f32_16x16x32_bf16(af, bfrag[ct], acc[t][ct], 0, 0, 0);
    }
    __syncthreads();  // all reads of buf done before it is re-staged
  }

  // D layout: col = lane&15 (lr), row = lg*4 + reg j
#pragma unroll
  for (int t = 0; t < 2; ++t) {
#pragma unroll
    for (int j = 0; j < 4; ++j) {
      const long R = (long)row0 + w * 32 + t * 16 + lg * 4 + j;
      if (R < Nrows) {
#pragma unroll
        for (int ct = 0; ct < 4; ++ct)
          Y[R * 64 + ct * 16 + lr] = acc[t][ct][j];
      }
    }
  }
}

// Y[N][64] = X[N][32] @ WB[64][32]^T, single k-step.
__global__ __launch_bounds__(256) void gemm_small(const float* __restrict__ X,
                                                  const __bf16* __restrict__ WB,
                                                  float* __restrict__ Y,
                                                  int Nrows) {
  const int tid = threadIdx.x;
  const int w = tid >> 6, l = tid & 63;
  const int lr = l & 15, lg = l >> 4;
  const long rowbase = (long)blockIdx.x * 64 + (long)w * 16;
  long r0 = rowbase + lr;
  if (r0 >= Nrows) r0 = Nrows - 1;
  const float* px = X + r0 * 32 + lg * 8;
  const __bf16* pw = WB + lr * 32 + lg * 8;

  const float4 lo = *reinterpret_cast<const float4*>(px);
  const float4 hi = *reinterpret_cast<const float4*>(px + 4);
  const bf16x8 af = cvt8(lo, hi);
  f32x4 acc[4];
#pragma unroll
  for (int j = 0; j < 4; ++j) acc[j] = (f32x4){0.f, 0.f, 0.f, 0.f};
#pragma unroll
  for (int t = 0; t < 4; ++t) {
    const bf16x8 bf = *reinterpret_cast<const bf16x8*>(pw + t * 16 * 32);
    acc[t] = __builtin_amdgcn_mfma_f32_16x16x32_bf16(af, bf, acc[t], 0, 0, 0);
  }
#pragma unroll
  for (int j = 0; j < 4; ++j) {
    const long R = rowbase + lg * 4 + j;
    if (R < Nrows) {
#pragma unroll
      for (int ct = 0; ct < 4; ++ct) Y[R * 64 + ct * 16 + lr] = acc[ct][j];
    }
  }
}

// ---------------- CSR build: counting sort edges by tgt ----------------

__global__ __launch_bounds__(256) void hist_deg(const int* __restrict__ ei,
                                                int* __restrict__ deg, int E) {
  const int e = blockIdx.x * 256 + threadIdx.x;
  if (e < E) atomicAdd(&deg[ei[E + e]], 1);
}

__global__ __launch_bounds__(256) void scan_tilesum(const int* __restrict__ deg,
                                                    int* __restrict__ tileSum,
                                                    int n) {
  __shared__ int s[256];
  const int b = blockIdx.x, t = threadIdx.x;
  const int base = b * 2048 + t * 8;
  int v = 0;
#pragma unroll
  for (int j = 0; j < 8; ++j) {
    const int i = base + j;
    if (i < n) v += deg[i];
  }
  s[t] = v;
  __syncthreads();
  for (int d = 128; d > 0; d >>= 1) {
    if (t < d) s[t] += s[t + d];
    __syncthreads();
  }
  if (t == 0) tileSum[b] = s[0];
}

__global__ __launch_bounds__(64) void scan_tileoff(const int* __restrict__ tileSum,
                                                   int* __restrict__ tileOff,
                                                   int nT) {
  const int l = threadIdx.x;
  const int v = (l < nT) ? tileSum[l] : 0;
  int inc = v;
#pragma unroll
  for (int d = 1; d < 64; d <<= 1) {
    const int o = __shfl_up(inc, d);
    if (l >= d) inc += o;
  }
  if (l < nT) tileOff[l] = inc - v;
}

__global__ __launch_bounds__(256) void scan_offsets(const int* __restrict__ deg,
                                                    const int* __restrict__ tileOff,
                                                    int* __restrict__ off, int n) {
  __shared__ int warpTot[4];
  const int b = blockIdx.x, t = threadIdx.x;
  const int base = b * 2048 + t * 8;
  int v[8];
  int s = 0;
#pragma unroll
  for (int j = 0; j < 8; ++j) {
    const int i = base + j;
    v[j] = (i < n) ? deg[i] : 0;
    s += v[j];
  }
  const int l = t & 63, w = t >> 6;
  int inc = s;
#pragma unroll
  for (int d = 1; d < 64; d <<= 1) {
    const int o = __shfl_up(inc, d);
    if (l >= d) inc += o;
  }
  if (l == 63) warpTot[w] = inc;
  __syncthreads();
  int wo = 0;
  for (int k = 0; k < w; ++k) wo += warpTot[k];
  int ex = wo + (inc - s) + tileOff[b];
#pragma unroll
  for (int j = 0; j < 8; ++j) {
    const int i = base + j;
    if (i < n) {
      off[i] = ex;
      ex += v[j];
    }
  }
}

__global__ __launch_bounds__(256) void scatter_src(const int* __restrict__ ei,
                                                   const int* __restrict__ off,
                                                   int* __restrict__ fill,
                                                   int* __restrict__ ssrc,
                                                   int E) {
  const int e = blockIdx.x * 256 + threadIdx.x;
  if (e < E) {
    const int t = ei[E + e];
    const int p = off[t] + atomicAdd(&fill[t], 1);
    ssrc[p] = ei[e];
  }
}

// ---------------- fused aggregation ----------------
template <int FINAL>
__global__ __launch_bounds__(256) void agg_fused(
    const int* __restrict__ off, const int* __restrict__ deg,
    const int* __restrict__ ssrc, const float* __restrict__ Y,
    const float* __restrict__ bias, float* __restrict__ out, int N) {
  const int t = blockIdx.x * 256 + threadIdx.x;
  const int i = t >> 5, c = t & 31;
  if (i >= N) return;
  const int st = off[i], d = deg[i];
  float acc = 0.0f;
  int e = 0;
  for (; e + 4 <= d; e += 4) {
    const int s0 = ssrc[st + e + 0];
    const int s1 = ssrc[st + e + 1];
    const int s2 = ssrc[st + e + 2];
    const int s3 = ssrc[st + e + 3];
    acc += Y[(long)s0 * 64 + c] + Y[(long)s1 * 64 + c] +
           Y[(long)s2 * 64 + c] + Y[(long)s3 * 64 + c];
  }
  for (; e < d; ++e) acc += Y[(long)ssrc[st + e] * 64 + c];
  const float mean = acc / fmaxf((float)d, 1.0f);
  float v = mean + bias[c] + Y[(long)i * 64 + 32 + c];
  if (FINAL) {
    v = fmaxf(v, 0.0f);
    float m = v;
#pragma unroll
    for (int dd = 16; dd >= 1; dd >>= 1) m = fmaxf(m, __shfl_xor(m, dd));
    const float ex = __expf(v - m);
    float s = ex;
#pragma unroll
    for (int dd = 16; dd >= 1; dd >>= 1) s += __shfl_xor(s, dd);
    out[(long)i * 32 + c] = (v - m) - __logf(s);
  } else {
    out[(long)i * 32 + c] = v;
  }
}

extern "C" void kernel_launch(void* const* d_in, const int* in_sizes, int n_in,
                              void* d_out, int out_size, void* d_ws,
                              size_t ws_size, hipStream_t stream) {
  const float* x = (const float*)d_in[0];
  const int* ei = (const int*)d_in[1];
  const float* W1l = (const float*)d_in[2];
  const float* b1l = (const float*)d_in[3];
  const float* W1r = (const float*)d_in[4];
  const float* W2l = (const float*)d_in[5];
  const float* b2l = (const float*)d_in[6];
  const float* W2r = (const float*)d_in[7];
  float* out = (float*)d_out;

  const int N = in_sizes[0] / K1;
  const int E = in_sizes[1] / 2;
  const int nTiles = (N + 2047) / 2048;

  char* ws = (char*)d_ws;
  size_t o = 0;
  auto alloc = [&](size_t bytes) {
    void* p = ws + o;
    o += (bytes + 255) & ~(size_t)255;
    return p;
  };
  float* ycomb = (float*)alloc((size_t)N * 64 * 4);
  float* h = (float*)alloc((size_t)N * 32 * 4);
  __bf16* wb1 = (__bf16*)alloc((size_t)64 * KP1 * 2);
  __bf16* wb2 = (__bf16*)alloc((size_t)64 * 32 * 2);
  int* deg = (int*)alloc((size_t)N * 4);
  int* off = (int*)alloc((size_t)N * 4);
  int* fill = (int*)alloc((size_t)N * 4);
  int* ssrc = (int*)alloc((size_t)E * 4);
  int* tileSum = (int*)alloc(64 * 4);
  int* tileOff = (int*)alloc(64 * 4);

  conv_w<<<(64 * KP1 + 255) / 256, 256, 0, stream>>>(W1l, W1r, wb1, K1, KP1);
  conv_w<<<(64 * 32 + 255) / 256, 256, 0, stream>>>(W2l, W2r, wb2, 32, 32);
  (void)hipMemsetAsync(deg, 0, (size_t)N * 4, stream);
  (void)hipMemsetAsync(fill, 0, (size_t)N * 4, stream);
  hist_deg<<<(E + 255) / 256, 256, 0, stream>>>(ei, deg, E);
  scan_tilesum<<<nTiles, 256, 0, stream>>>(deg, tileSum, N);
  scan_tileoff<<<1, 64, 0, stream>>>(tileSum, tileOff, nTiles);
  scan_offsets<<<nTiles, 256, 0, stream>>>(deg, tileOff, off, N);
  scatter_src<<<(E + 255) / 256, 256, 0, stream>>>(ei, off, fill, ssrc, E);

  // Layer 1
  gemm_big<<<(N + BM - 1) / BM, 256, 0, stream>>>(x, wb1, ycomb, N);
  agg_fused<0><<<(N * 32 + 255) / 256, 256, 0, stream>>>(off, deg, ssrc, ycomb,
                                                         b1l, h, N);
  // Layer 2
  gemm_small<<<(N + 63) / 64, 256, 0, stream>>>(h, wb2, ycomb, N);
  agg_fused<1><<<(N * 32 + 255) / 256, 256, 0, stream>>>(off, deg, ssrc, ycomb,
                                                         b2l, out, N);
}

// Round 8
// 300.800 us; speedup vs baseline: 1.1927x; 1.0019x over previous
//
#include <hip/hip_runtime.h>
#include <hip/hip_bf16.h>

// GraphSAGE 2-layer. Project-then-aggregate (aggregation is linear):
//   ycomb = x @ [W1l|W1r]^T   (bf16 MFMA; A+B staged via global_load_lds,
//                              counted vmcnt(5) across raw barriers — T4)
//   CSR build (once): counting-sort edges by tgt
//   h     = csr_mean(ycomb[:, :32]) + b1l + ycomb[:,32:]
//   ycomb = h @ [W2l|W2r]^T
//   out   = log_softmax(relu(csr_mean(ycomb[:, :32]) + b2l + ycomb[:,32:]))

typedef __attribute__((ext_vector_type(8))) __bf16 bf16x8;
typedef __attribute__((ext_vector_type(4))) float f32x4;

constexpr int K1 = 1433;
constexpr int KP1 = 1536;  // B pad (bf16): no B guards anywhere
constexpr int BK = 32;     // k per step
constexpr int NS = 45;     // ceil(1433/32); k>=1433 contributes A*0 via B pad
constexpr int BM = 128;    // rows per block

__device__ __forceinline__ void gload_lds16(const void* g, void* l) {
  __builtin_amdgcn_global_load_lds(
      reinterpret_cast<const __attribute__((address_space(1))) void*>(
          reinterpret_cast<uintptr_t>(g)),
      reinterpret_cast<__attribute__((address_space(3))) void*>(
          reinterpret_cast<uintptr_t>(l)),
      16, 0, 0);
}

__device__ __forceinline__ bf16x8 cvt8(const float4 lo, const float4 hi) {
  bf16x8 r;
  r[0] = (__bf16)lo.x; r[1] = (__bf16)lo.y;
  r[2] = (__bf16)lo.z; r[3] = (__bf16)lo.w;
  r[4] = (__bf16)hi.x; r[5] = (__bf16)hi.y;
  r[6] = (__bf16)hi.z; r[7] = (__bf16)hi.w;
  return r;
}

// Convert [W_l; W_r] (each 32 x K fp32) into WB[64][KP] bf16, zero-padded.
__global__ __launch_bounds__(256) void conv_w(const float* __restrict__ Wl,
                                              const float* __restrict__ Wr,
                                              __bf16* __restrict__ out, int K,
                                              int KP) {
  const int t = blockIdx.x * 256 + threadIdx.x;
  if (t >= 64 * KP) return;
  const int c = t / KP, k = t - c * KP;
  float v = 0.0f;
  if (k < K) v = (c < 32) ? Wl[(long)c * K + k] : Wr[(long)(c - 32) * K + k];
  out[t] = (__bf16)v;
}

// Y[N][64] = X[N][1433] @ WB[64][1536]^T.
// K-loop global traffic is exclusively global_load_lds; compute reads LDS
// only. T4: stage(s+1) stays IN FLIGHT across the barrier — wait vmcnt(5)
// (= stage(s) retired), never 0, so each wave always has 5 KB outstanding.
__global__ __launch_bounds__(256) void gemm_big(const float* __restrict__ X,
                                                const __bf16* __restrict__ WB,
                                                float* __restrict__ Y,
                                                int Nrows) {
  __shared__ float ldsA[2][BM][BK];      // 2 x 16 KB
  __shared__ __bf16 ldsB[2][64][BK];     // 2 x 4 KB
  const int tid = threadIdx.x;
  const int w = tid >> 6, l = tid & 63;
  const int lr = l & 15, lg = l >> 4;
  const int row0 = blockIdx.x * BM;

  // A instr i (i=0..3): lane l -> global row row0+w*32+i*8+(l>>3),
  //                     chunk (l&7)^(l>>3); LDS dest base (w*32+i*8) row.
  const int aRowIn = (l >> 3);            // 0..7
  const int aChunk = (l & 7) ^ aRowIn;    // swizzled 16B chunk
  long aRow[4];
#pragma unroll
  for (int i = 0; i < 4; ++i) {
    long r = (long)row0 + w * 32 + i * 8 + aRowIn;
    if (r >= Nrows) r = Nrows - 1;
    aRow[i] = r;
  }
  const float* const pAmax = X + (size_t)Nrows * K1 - 4;  // clamp: stay in buf
  // B: lane l -> row w*16+(l>>2), chunk (l&3)^((l>>3)&3)
  const int bRow = w * 16 + (l >> 2);
  const int bChunk = (l & 3) ^ ((l >> 3) & 3);
  const __bf16* const pB0 = WB + (long)bRow * KP1 + bChunk * 8;

  auto stage = [&](int s, int buf) {
    const int k0 = s * BK;
#pragma unroll
    for (int i = 0; i < 4; ++i) {
      const float* g = X + aRow[i] * K1 + k0 + aChunk * 4;
      if (g > pAmax) g = pAmax;  // finite garbage * B-zero-pad = 0
      gload_lds16(g, &ldsA[buf][w * 32 + i * 8][0]);
    }
    gload_lds16(pB0 + k0, &ldsB[buf][w * 16][0]);
  };

  f32x4 acc[2][4];
#pragma unroll
  for (int t = 0; t < 2; ++t)
#pragma unroll
    for (int j = 0; j < 4; ++j) acc[t][j] = (f32x4){0.f, 0.f, 0.f, 0.f};

  const int swzA = lr & 7;          // row&7 for this lane's A-frag rows
  const int swzB = (lr >> 1) & 3;   // (row>>1)&3 for this lane's B-frag rows

  stage(0, 0);
#pragma unroll 1
  for (int s = 0; s < NS; ++s) {
    const int buf = s & 1;
    if (s + 1 < NS) {
      stage(s + 1, buf ^ 1);  // 10 outstanding/wave
      // retire the oldest 5 (= stage(s)); keep stage(s+1) in flight
      asm volatile("s_waitcnt vmcnt(5)" ::: "memory");
    } else {
      asm volatile("s_waitcnt vmcnt(0)" ::: "memory");
    }
    __builtin_amdgcn_s_barrier();       // all waves: their stage(s) retired
    __builtin_amdgcn_sched_barrier(0);  // fence: no ds_read hoisted above
    // ---- compute from LDS only ----
    bf16x8 bfrag[4];
#pragma unroll
    for (int ct = 0; ct < 4; ++ct) {
      const int br = ct * 16 + lr;
      bfrag[ct] = *reinterpret_cast<const bf16x8*>(
          &ldsB[buf][br][(lg ^ swzB) * 8]);
    }
#pragma unroll
    for (int t = 0; t < 2; ++t) {
      const int fr = w * 32 + t * 16 + lr;
      const float4 u = *reinterpret_cast<const float4*>(
          &ldsA[buf][fr][((lg * 2 + 0) ^ swzA) * 4]);
      const float4 v = *reinterpret_cast<const float4*>(
          &ldsA[buf][fr][((lg * 2 + 1) ^ swzA) * 4]);
      const bf16x8 af = cvt8(u, v);
#pragma unroll
      for (int ct = 0; ct < 4; ++ct)
        acc[t][ct] =
            __builtin_amdgcn_mfma_f32_16x16x32_bf16(af, bfrag[ct], acc[t][ct], 0, 0, 0);
    }
    __builtin_amdgcn_sched_barrier(0);  // all reads issued before barrier
    __builtin_amdgcn_s_barrier();       // reads of buf done before re-stage
  }

  // D layout: col = lane&15 (lr), row = lg*4 + reg j
#pragma unroll
  for (int t = 0; t < 2; ++t) {
#pragma unroll
    for (int j = 0; j < 4; ++j) {
      const long R = (long)row0 + w * 32 + t * 16 + lg * 4 + j;
      if (R < Nrows) {
#pragma unroll
        for (int ct = 0; ct < 4; ++ct)
          Y[R * 64 + ct * 16 + lr] = acc[t][ct][j];
      }
    }
  }
}

// Y[N][64] = X[N][32] @ WB[64][32]^T, single k-step.
__global__ __launch_bounds__(256) void gemm_small(const float* __restrict__ X,
                                                  const __bf16* __restrict__ WB,
                                                  float* __restrict__ Y,
                                                  int Nrows) {
  const int tid = threadIdx.x;
  const int w = tid >> 6, l = tid & 63;
  const int lr = l & 15, lg = l >> 4;
  const long rowbase = (long)blockIdx.x * 64 + (long)w * 16;
  long r0 = rowbase + lr;
  if (r0 >= Nrows) r0 = Nrows - 1;
  const float* px = X + r0 * 32 + lg * 8;
  const __bf16* pw = WB + lr * 32 + lg * 8;

  const float4 lo = *reinterpret_cast<const float4*>(px);
  const float4 hi = *reinterpret_cast<const float4*>(px + 4);
  const bf16x8 af = cvt8(lo, hi);
  f32x4 acc[4];
#pragma unroll
  for (int j = 0; j < 4; ++j) acc[j] = (f32x4){0.f, 0.f, 0.f, 0.f};
#pragma unroll
  for (int t = 0; t < 4; ++t) {
    const bf16x8 bf = *reinterpret_cast<const bf16x8*>(pw + t * 16 * 32);
    acc[t] = __builtin_amdgcn_mfma_f32_16x16x32_bf16(af, bf, acc[t], 0, 0, 0);
  }
#pragma unroll
  for (int j = 0; j < 4; ++j) {
    const long R = rowbase + lg * 4 + j;
    if (R < Nrows) {
#pragma unroll
      for (int ct = 0; ct < 4; ++ct) Y[R * 64 + ct * 16 + lr] = acc[ct][j];
    }
  }
}

// ---------------- CSR build: counting sort edges by tgt ----------------

__global__ __launch_bounds__(256) void hist_deg(const int* __restrict__ ei,
                                                int* __restrict__ deg, int E) {
  const int e = blockIdx.x * 256 + threadIdx.x;
  if (e < E) atomicAdd(&deg[ei[E + e]], 1);
}

__global__ __launch_bounds__(256) void scan_tilesum(const int* __restrict__ deg,
                                                    int* __restrict__ tileSum,
                                                    int n) {
  __shared__ int s[256];
  const int b = blockIdx.x, t = threadIdx.x;
  const int base = b * 2048 + t * 8;
  int v = 0;
#pragma unroll
  for (int j = 0; j < 8; ++j) {
    const int i = base + j;
    if (i < n) v += deg[i];
  }
  s[t] = v;
  __syncthreads();
  for (int d = 128; d > 0; d >>= 1) {
    if (t < d) s[t] += s[t + d];
    __syncthreads();
  }
  if (t == 0) tileSum[b] = s[0];
}

__global__ __launch_bounds__(64) void scan_tileoff(const int* __restrict__ tileSum,
                                                   int* __restrict__ tileOff,
                                                   int nT) {
  const int l = threadIdx.x;
  const int v = (l < nT) ? tileSum[l] : 0;
  int inc = v;
#pragma unroll
  for (int d = 1; d < 64; d <<= 1) {
    const int o = __shfl_up(inc, d);
    if (l >= d) inc += o;
  }
  if (l < nT) tileOff[l] = inc - v;
}

__global__ __launch_bounds__(256) void scan_offsets(const int* __restrict__ deg,
                                                    const int* __restrict__ tileOff,
                                                    int* __restrict__ off, int n) {
  __shared__ int warpTot[4];
  const int b = blockIdx.x, t = threadIdx.x;
  const int base = b * 2048 + t * 8;
  int v[8];
  int s = 0;
#pragma unroll
  for (int j = 0; j < 8; ++j) {
    const int i = base + j;
    v[j] = (i < n) ? deg[i] : 0;
    s += v[j];
  }
  const int l = t & 63, w = t >> 6;
  int inc = s;
#pragma unroll
  for (int d = 1; d < 64; d <<= 1) {
    const int o = __shfl_up(inc, d);
    if (l >= d) inc += o;
  }
  if (l == 63) warpTot[w] = inc;
  __syncthreads();
  int wo = 0;
  for (int k = 0; k < w; ++k) wo += warpTot[k];
  int ex = wo + (inc - s) + tileOff[b];
#pragma unroll
  for (int j = 0; j < 8; ++j) {
    const int i = base + j;
    if (i < n) {
      off[i] = ex;
      ex += v[j];
    }
  }
}

__global__ __launch_bounds__(256) void scatter_src(const int* __restrict__ ei,
                                                   const int* __restrict__ off,
                                                   int* __restrict__ fill,
                                                   int* __restrict__ ssrc,
                                                   int E) {
  const int e = blockIdx.x * 256 + threadIdx.x;
  if (e < E) {
    const int t = ei[E + e];
    const int p = off[t] + atomicAdd(&fill[t], 1);
    ssrc[p] = ei[e];
  }
}

// ---------------- fused aggregation ----------------
template <int FINAL>
__global__ __launch_bounds__(256) void agg_fused(
    const int* __restrict__ off, const int* __restrict__ deg,
    const int* __restrict__ ssrc, const float* __restrict__ Y,
    const float* __restrict__ bias, float* __restrict__ out, int N) {
  const int t = blockIdx.x * 256 + threadIdx.x;
  const int i = t >> 5, c = t & 31;
  if (i >= N) return;
  const int st = off[i], d = deg[i];
  float acc = 0.0f;
  int e = 0;
  for (; e + 4 <= d; e += 4) {
    const int s0 = ssrc[st + e + 0];
    const int s1 = ssrc[st + e + 1];
    const int s2 = ssrc[st + e + 2];
    const int s3 = ssrc[st + e + 3];
    acc += Y[(long)s0 * 64 + c] + Y[(long)s1 * 64 + c] +
           Y[(long)s2 * 64 + c] + Y[(long)s3 * 64 + c];
  }
  for (; e < d; ++e) acc += Y[(long)ssrc[st + e] * 64 + c];
  const float mean = acc / fmaxf((float)d, 1.0f);
  float v = mean + bias[c] + Y[(long)i * 64 + 32 + c];
  if (FINAL) {
    v = fmaxf(v, 0.0f);
    float m = v;
#pragma unroll
    for (int dd = 16; dd >= 1; dd >>= 1) m = fmaxf(m, __shfl_xor(m, dd));
    const float ex = __expf(v - m);
    float s = ex;
#pragma unroll
    for (int dd = 16; dd >= 1; dd >>= 1) s += __shfl_xor(s, dd);
    out[(long)i * 32 + c] = (v - m) - __logf(s);
  } else {
    out[(long)i * 32 + c] = v;
  }
}

extern "C" void kernel_launch(void* const* d_in, const int* in_sizes, int n_in,
                              void* d_out, int out_size, void* d_ws,
                              size_t ws_size, hipStream_t stream) {
  const float* x = (const float*)d_in[0];
  const int* ei = (const int*)d_in[1];
  const float* W1l = (const float*)d_in[2];
  const float* b1l = (const float*)d_in[3];
  const float* W1r = (const float*)d_in[4];
  const float* W2l = (const float*)d_in[5];
  const float* b2l = (const float*)d_in[6];
  const float* W2r = (const float*)d_in[7];
  float* out = (float*)d_out;

  const int N = in_sizes[0] / K1;
  const int E = in_sizes[1] / 2;
  const int nTiles = (N + 2047) / 2048;

  char* ws = (char*)d_ws;
  size_t o = 0;
  auto alloc = [&](size_t bytes) {
    void* p = ws + o;
    o += (bytes + 255) & ~(size_t)255;
    return p;
  };
  float* ycomb = (float*)alloc((size_t)N * 64 * 4);
  float* h = (float*)alloc((size_t)N * 32 * 4);
  __bf16* wb1 = (__bf16*)alloc((size_t)64 * KP1 * 2);
  __bf16* wb2 = (__bf16*)alloc((size_t)64 * 32 * 2);
  int* deg = (int*)alloc((size_t)N * 4);
  int* off = (int*)alloc((size_t)N * 4);
  int* fill = (int*)alloc((size_t)N * 4);
  int* ssrc = (int*)alloc((size_t)E * 4);
  int* tileSum = (int*)alloc(64 * 4);
  int* tileOff = (int*)alloc(64 * 4);

  conv_w<<<(64 * KP1 + 255) / 256, 256, 0, stream>>>(W1l, W1r, wb1, K1, KP1);
  conv_w<<<(64 * 32 + 255) / 256, 256, 0, stream>>>(W2l, W2r, wb2, 32, 32);
  (void)hipMemsetAsync(deg, 0, (size_t)N * 4, stream);
  (void)hipMemsetAsync(fill, 0, (size_t)N * 4, stream);
  hist_deg<<<(E + 255) / 256, 256, 0, stream>>>(ei, deg, E);
  scan_tilesum<<<nTiles, 256, 0, stream>>>(deg, tileSum, N);
  scan_tileoff<<<1, 64, 0, stream>>>(tileSum, tileOff, nTiles);
  scan_offsets<<<nTiles, 256, 0, stream>>>(deg, tileOff, off, N);
  scatter_src<<<(E + 255) / 256, 256, 0, stream>>>(ei, off, fill, ssrc, E);

  // Layer 1
  gemm_big<<<(N + BM - 1) / BM, 256, 0, stream>>>(x, wb1, ycomb, N);
  agg_fused<0><<<(N * 32 + 255) / 256, 256, 0, stream>>>(off, deg, ssrc, ycomb,
                                                         b1l, h, N);
  // Layer 2
  gemm_small<<<(N + 63) / 64, 256, 0, stream>>>(h, wb2, ycomb, N);
  agg_fused<1><<<(N * 32 + 255) / 256, 256, 0, stream>>>(off, deg, ssrc, ycomb,
                                                         b2l, out, N);
}